// Round 9
// baseline (3169.076 us; speedup 1.0000x reference)
//
#include <hip/hip_runtime.h>
#include <hip/hip_bf16.h>
#include <math.h>

// T=128, B=32, D=512, H=512, N=64, A=32, TAU=1
#define NTHR  512
#define NBLK  224              // 32 BC blocks + 192 GEMM blocks
#define HTXS  20480            // hTx buffer stride: [32][640]

// ---- flag area (int offsets into d_ws) ----
// hflag[b]     = bar[b*32]                  (BC b plain sc1-stores t+1)
// wflag(cg,b)  = bar[2048 + (cg*32+b)*16]   (GEMM wave stores t+1 per batch)
#define OFF_HTX  65536                      // hTx_all: [129][32][640]
#define OFF_OC   (OFF_HTX + 129*HTXS)       // oc: [32][4608]
#define OFF_HNEW (OFF_OC + 32*4608)         // hnew_part: [32][64][512]
#define OFF_WHH  (OFF_HNEW + 32*64*512)     // whh_part: [32][64][1536]
#define OFF_C0   (OFF_WHH + 32*64*1536)     // c0: [1536]
#define OFF_W2   (OFF_C0 + 1536)            // W2: [96][576][48] col-group-major
#define OFF_MTMP (OFF_W2 + 96*27648)        // Mtmp: [512][1536]
#define OFF_P1   (OFF_MTMP + 512*1536)      // P1: [4096][1536]
#define OFF_P2   (OFF_P1 + 4096*1536)       // P2: [4096][512]
// end = OFF_P2 + 4096*512 = 18,880,000 floats = 75.5 MB (< 76.5 known-good)

// sc1 (agent-scope) ops: bypass per-XCD L2, coherent at LLC. Used for flags,
// oc (step-reused), and hTx writes. hTx READS are normal cached loads
// (rotating buffers, write-once-then-read — validated r2/r3/r8).
__device__ __forceinline__ float cohLoad(const float* p) {
  return __hip_atomic_load(p, __ATOMIC_RELAXED, __HIP_MEMORY_SCOPE_AGENT);
}
__device__ __forceinline__ void cohStore(float* p, float v) {
  __hip_atomic_store(p, v, __ATOMIC_RELAXED, __HIP_MEMORY_SCOPE_AGENT);
}
__device__ __forceinline__ int cohLoadI(const int* p) {
  return __hip_atomic_load(p, __ATOMIC_RELAXED, __HIP_MEMORY_SCOPE_AGENT);
}
__device__ __forceinline__ void cohStoreI(int* p, int v) {
  __hip_atomic_store(p, v, __ATOMIC_RELAXED, __HIP_MEMORY_SCOPE_AGENT);
}

// ---------------------------------------------------------------------------
// Generic tiled fp32 GEMM (pre-pass only)
// ---------------------------------------------------------------------------
__global__ __launch_bounds__(256) void gemm_f32(
    const float* __restrict__ A, const float* __restrict__ B,
    const float* __restrict__ bias, float* __restrict__ C,
    int M, int N, int K, int lda, int ldb, int ldc)
{
  __shared__ float As[16][132];
  __shared__ float Bs[16][64];
  const int bm = blockIdx.x * 128, bn = blockIdx.y * 64;
  const int tid = threadIdx.x;
  const int tx = tid & 15, ty = tid >> 4;
  float acc[8][4];
  #pragma unroll
  for (int i = 0; i < 8; ++i)
    #pragma unroll
    for (int j = 0; j < 4; ++j) acc[i][j] = 0.f;

  for (int kt = 0; kt < K; kt += 16) {
    #pragma unroll
    for (int i = 0; i < 2; ++i) {
      int li = tid + i*256;
      int r = li >> 2, q = li & 3;
      float4 a4 = *(const float4*)(A + (size_t)(bm + r)*lda + kt + q*4);
      As[q*4+0][r] = a4.x; As[q*4+1][r] = a4.y;
      As[q*4+2][r] = a4.z; As[q*4+3][r] = a4.w;
    }
    {
      int k = tid >> 4, nq = tid & 15;
      *(float4*)(&Bs[k][nq*4]) = *(const float4*)(B + (size_t)(kt + k)*ldb + bn + nq*4);
    }
    __syncthreads();
    #pragma unroll
    for (int kk = 0; kk < 16; ++kk) {
      float av[8], bv[4];
      *(float4*)(av)   = *(const float4*)(&As[kk][ty*8]);
      *(float4*)(av+4) = *(const float4*)(&As[kk][ty*8+4]);
      *(float4*)(bv)   = *(const float4*)(&Bs[kk][tx*4]);
      #pragma unroll
      for (int i = 0; i < 8; ++i)
        #pragma unroll
        for (int j = 0; j < 4; ++j) acc[i][j] += av[i]*bv[j];
    }
    __syncthreads();
  }
  #pragma unroll
  for (int i = 0; i < 8; ++i) {
    int m = bm + ty*8 + i;
    #pragma unroll
    for (int j = 0; j < 4; ++j) {
      int n = bn + tx*4 + j;
      float v = acc[i][j];
      if (bias) v += bias[n];
      C[(size_t)m*ldc + n] = v;
    }
  }
}

// ---------------------------------------------------------------------------
// Setup: W2 [96 col-groups][576 k][48 c] static parts + zero M-rows + c0.
// Global col C = cg*48+c48. C<512: W_hm/W_um; 512..1023: fc2_A; 1024..1535:
// fc2_B (rows 512:576 zero); cols 1536:4608 rows 512:576 zero (M_A/M_B rows
// 0:512 filled later by GEMM+transpose).
// ---------------------------------------------------------------------------
__global__ __launch_bounds__(512) void setup_kernel(
    const float* __restrict__ W_hm, const float* __restrict__ fc2_w,
    const float* __restrict__ W_um, const float* __restrict__ W_hh,
    const float* __restrict__ bias, const float* __restrict__ fc2_b,
    float* __restrict__ W2, float* __restrict__ c0)
{
  const int idx = blockIdx.x * 512 + threadIdx.x;
  if (idx < 884736) {                         // cg 0..31 (cols 0:1536), all k
    int cg = idx / 27648, rem = idx % 27648, k = rem / 48, c48 = rem % 48;
    int C = cg*48 + c48;
    float v;
    if (C < 512)       v = (k < 512) ? W_hm[k*512 + C] : W_um[(k-512)*512 + C];
    else if (C < 1024) v = (k < 512) ? fc2_w[(size_t)k*512 + (C-512)] : 0.f;
    else               v = (k < 512) ? fc2_w[(size_t)(512+k)*512 + (C-1024)] : 0.f;
    W2[idx] = v;
    return;
  }
  int i = idx - 884736;
  if (i < 196608) {                           // cg 32..95, rows 512:576 = 0
    int cg = 32 + i / 3072, rem = i % 3072, k = 512 + rem / 48, c48 = rem % 48;
    W2[(size_t)cg*27648 + k*48 + c48] = 0.f;
    return;
  }
  i -= 196608;
  if (i < 1536) {                             // c0 = fc2_b@W_hh + bias_hh
    float s = bias[1536 + i];
    for (int m = 0; m < 512; ++m) s += fc2_b[m] * W_hh[(size_t)m*1536 + i];
    c0[i] = s;
  }
}

// W2 cols [baseCg*48, baseCg*48+1536) rows 0:512  <-  Mtmp[512][1536]
__global__ __launch_bounds__(512) void trans_kernel(
    const float* __restrict__ Mtmp, float* __restrict__ W2, int baseCg)
{
  const int idx = blockIdx.x * 512 + threadIdx.x;   // 32*512*48 = 786432
  int cgrel = idx / 24576, rem = idx % 24576, k = rem / 48, c48 = rem % 48;
  W2[(size_t)(baseCg + cgrel)*27648 + k*48 + c48] =
      Mtmp[(size_t)k*1536 + cgrel*48 + c48];
}

// ---------------------------------------------------------------------------
// Persistent scan. Blocks 0..31: BC (batch b). Blocks 32..223: GEMM.
// GEMM block gb: cg = gb>>1 (48 cols), 8 INDEPENDENT waves; wave w = pair
// p = (gb&1)*8+w handles batches 2p, 2p+1 with per-batch flags. No
// __syncthreads in the GEMM path — 1536 decoupled wave pipelines.
// Batches are independent -> no global per-step barrier anywhere.
// ---------------------------------------------------------------------------
__global__ __launch_bounds__(NTHR, 1) void persist_kernel(
    const float* __restrict__ P1, const float* __restrict__ P2,
    const float* __restrict__ W2, float* __restrict__ oc,
    float* __restrict__ hTx_all, float* __restrict__ hnew_part,
    float* __restrict__ whh_part, const float* __restrict__ c0,
    const float* __restrict__ fc1_w, const float* __restrict__ fc1_b,
    const float* __restrict__ fc2_b, const float* __restrict__ u_noise,
    const int* __restrict__ length, const float* __restrict__ fc_w,
    const float* __restrict__ fc_b, float* __restrict__ out,
    int* __restrict__ bar)
{
  __shared__ float smem[5632];     // GEMM: 8 waves x 704-float h slots; BC: scratch
  const int bid = blockIdx.x;
  const int tid = threadIdx.x;

  if (bid >= 32) {
    // ================= GEMM block: 48 cols, 8 independent waves ===========
    const int gb   = bid - 32;           // 0..191
    const int cg   = gb >> 1;            // 0..95
    const int p    = (gb & 1)*8 + (tid >> 6);   // pair 0..15
    const int lane = tid & 63;
    const int k8   = lane >> 3;          // K-group 0..7 (72 rows)
    const int c8   = lane & 7;           // col-group 0..7 (6 cols)
    const float* wcg = W2 + (size_t)cg*27648;
    float* myh = smem + (tid >> 6)*704;  // this wave's h slot
    int* myhflag0 = &bar[(p*2)*32];
    int* myhflag1 = &bar[(p*2+1)*32];

    for (int t = 0; t < 128; ++t) {
      #pragma unroll
      for (int ii = 0; ii < 2; ++ii) {
        const int sel = (t + ii) & 1;    // alternate batch priority per step
        const int b = p*2 + sel;
        int* hf = sel ? myhflag1 : myhflag0;
        while (cohLoadI(hf) < t) __builtin_amdgcn_s_sleep(1);
        __threadfence_block();           // compiler+waitcnt barrier, no cache ops
        // stage h(t) for batch b: 576 floats, coalesced cached loads -> LDS
        const float* hb = hTx_all + (size_t)t*HTXS + b*640;
        #pragma unroll
        for (int j = 0; j < 9; ++j) myh[j*64 + lane] = hb[j*64 + lane];
        __threadfence_block();           // ds_writes visible to whole wave
        // 6 cols x 72 k per lane
        float a0=0.f,a1=0.f,a2=0.f,a3=0.f,a4=0.f,a5=0.f;
        const float* wp = wcg + (size_t)(k8*72)*48 + c8*6;
        const float* hp = myh + k8*72;
        #pragma unroll 4
        for (int kk = 0; kk < 72; ++kk) {
          float h = hp[kk];
          float2 w01 = *(const float2*)(wp);
          float2 w23 = *(const float2*)(wp + 2);
          float2 w45 = *(const float2*)(wp + 4);
          wp += 48;
          a0 += h*w01.x; a1 += h*w01.y; a2 += h*w23.x;
          a3 += h*w23.y; a4 += h*w45.x; a5 += h*w45.y;
        }
        // reduce over k8 (lane bits 3..5)
        #pragma unroll
        for (int off = 8; off <= 32; off <<= 1) {
          a0 += __shfl_xor(a0, off); a1 += __shfl_xor(a1, off);
          a2 += __shfl_xor(a2, off); a3 += __shfl_xor(a3, off);
          a4 += __shfl_xor(a4, off); a5 += __shfl_xor(a5, off);
        }
        if (k8 == 0) {                   // lanes 0..7 store 6 cols each
          float* op = oc + (size_t)b*4608 + cg*48 + c8*6;
          cohStore(op+0,a0); cohStore(op+1,a1); cohStore(op+2,a2);
          cohStore(op+3,a3); cohStore(op+4,a4); cohStore(op+5,a5);
        }
        __threadfence_block();           // drain oc stores (vmcnt 0)
        if (lane == 0) cohStoreI(&bar[2048 + (cg*32 + b)*16], t + 1);
      }
    }
  } else {
    // ================= BC block: batch b =================
    const int b = bid;
    const int lenb = length[b];
    float hcur = 0.f;
    float usage_r = -99999.f;            // valid for tid<64
    int jprev = 0;                       // thread-0 only
    int* flg = (int*)(smem + 1100);
    const float c0r = c0[tid], c0z = c0[512 + tid], c0n = c0[1024 + tid];
    const float fc2bv = fc2_b[tid];
    const float f1b = (tid < 64) ? fc1_b[tid] : 0.f;
    const int n_ = tid & 63, kg_ = tid >> 6;
    const float* fw = fc1_w + (size_t)kg_*64*64 + n_;

    for (int t = 0; t < 128; ++t) {
      const int t32b = t*32 + b;
      // prefetch step inputs (independent of flags)
      const float* p1p = P1 + (size_t)t32b*1536;
      float p1r = p1p[tid], p1z = p1p[512 + tid], p1n = p1p[1024 + tid];
      float p2v = P2[(size_t)t32b*512 + tid];
      float uval = (tid < 64) ? u_noise[(size_t)t32b*64 + tid] : 0.f;
      // ---- wait EARLY col-groups for THIS batch (cg 0..31, cols 0:1536) ----
      if (tid < 32) {
        while (cohLoadI(&bar[2048 + (tid*32 + b)*16]) < t + 1)
          __builtin_amdgcn_s_sleep(1);
      }
      __syncthreads();
      const float* ocb = oc + (size_t)b*4608;
      float oct = cohLoad(ocb + tid);
      float vA  = cohLoad(ocb + 512  + tid);
      float vB  = cohLoad(ocb + 1024 + tid);
      smem[tid] = tanhf(p2v + oct);      // th
      __syncthreads();
      {                                  // fc1 partial dots
        float sdot = 0.f;
        #pragma unroll 8
        for (int k = 0; k < 64; ++k) sdot += smem[kg_*64 + k] * fw[(size_t)k*64];
        smem[512 + tid] = sdot;
      }
      __syncthreads();
      if (tid < 64) {                    // logits + Gumbel + wave argmax
        float l = f1b;
        #pragma unroll
        for (int kg = 0; kg < 8; ++kg) l += smem[512 + kg*64 + tid];
        l += -logf(1e-20f - logf(1e-20f + uval));
        float best = l; int idx = tid;
        #pragma unroll
        for (int off = 32; off >= 1; off >>= 1) {
          float ob = __shfl_xor(best, off);
          int   oi = __shfl_xor(idx,  off);
          if (ob > best || (ob == best && oi < idx)) { best = ob; idx = oi; }
        }
        if (tid == 0) {
          flg[0] = idx;
          flg[1] = (t < 64) ? t : jprev;
          jprev = idx;
        }
      }
      // ---- wait LATE col-groups for THIS batch (cg 32..95) ----
      if (tid < 64) {
        while (cohLoadI(&bar[2048 + ((32 + tid)*32 + b)*16]) < t + 1)
          __builtin_amdgcn_s_sleep(1);
      }
      __syncthreads();
      const int jj = flg[0], ss = flg[1];
      float vAW0 = cohLoad(ocb + 1536 + tid);
      float vAW1 = cohLoad(ocb + 2048 + tid);
      float vAW2 = cohLoad(ocb + 2560 + tid);
      float vBW0 = cohLoad(ocb + 3072 + tid);
      float vBW1 = cohLoad(ocb + 3584 + tid);
      float vBW2 = cohLoad(ocb + 4096 + tid);
      float hnp, w0, w1, w2;
      if (jj == ss) { hnp = vA; w0 = vAW0; w1 = vAW1; w2 = vAW2; }
      else {
        hnp = hnew_part[(size_t)(b*64 + jj)*512 + tid];
        const float* wpp = whh_part + (size_t)(b*64 + jj)*1536;
        w0 = wpp[tid]; w1 = wpp[512 + tid]; w2 = wpp[1024 + tid];
      }
      float h_new = hnp + vB + fc2bv;
      float wh_r = w0 + vBW0 + c0r;
      float wh_z = w1 + vBW1 + c0z;
      float wh_n = w2 + vBW2 + c0n;
      float r  = 1.f / (1.f + expf(-(p1r + wh_r)));
      float z  = 1.f / (1.f + expf(-(p1z + wh_z)));
      float nn = tanhf(p1n + r*wh_n);
      float h1 = (1.f - z)*nn + z*h_new;
      if (t >= lenb) h1 = hcur;
      hcur = h1;
      // publish h(t+1)+lu: batch-contiguous [b][640] (sc1 -> LLC)
      float* hw = hTx_all + (size_t)(t + 1)*HTXS + b*640;
      cohStore(&hw[tid], h1);
      if (tid < 64) {
        float un = (usage_r - 1.f) * (tid == jj ? 0.f : 1.f);
        usage_r = un;
        cohStore(&hw[512 + tid], 1.f / (1.f + expf(-un)));
      }
      smem[tid] = h1;                    // for out projection below
      __syncthreads();                   // drain sc1 stores
      if (tid == 0) cohStoreI(&bar[b*32], t + 1);
      // ---- off critical path: slot caches + output projection ----
      hnew_part[(size_t)(b*64 + ss)*512 + tid] = vA;
      float* wps = whh_part + (size_t)(b*64 + ss)*1536;
      wps[tid] = vAW0; wps[512 + tid] = vAW1; wps[1024 + tid] = vAW2;
      {
        int a = tid & 31, jg = tid >> 5;
        float sp = 0.f;
        #pragma unroll 8
        for (int jx = 0; jx < 32; ++jx)
          sp += smem[jg*32 + jx] * fc_w[(size_t)(jg*32 + jx)*32 + a];
        smem[512 + tid] = sp;
      }
      __syncthreads();
      if (tid < 32) {
        float s2 = fc_b[tid];
        #pragma unroll
        for (int jg = 0; jg < 16; ++jg) s2 += smem[512 + jg*32 + tid];
        out[(size_t)t32b*32 + tid] = s2;
      }
    }
  }
}

// ---------------------------------------------------------------------------
extern "C" void kernel_launch(void* const* d_in, const int* in_sizes, int n_in,
                              void* d_out, int out_size, void* d_ws, size_t ws_size,
                              hipStream_t stream)
{
  const float* x      = (const float*)d_in[0];
  const int*   length = (const int*)  d_in[1];
  const float* u_nois = (const float*)d_in[2];
  const float* W_ih   = (const float*)d_in[3];
  const float* W_hh   = (const float*)d_in[4];
  const float* bias   = (const float*)d_in[5];
  const float* W_im   = (const float*)d_in[6];
  const float* W_hm   = (const float*)d_in[7];
  const float* W_um   = (const float*)d_in[8];
  const float* fc1_w  = (const float*)d_in[9];
  const float* fc1_b  = (const float*)d_in[10];
  const float* fc2_w  = (const float*)d_in[11];
  const float* fc2_b  = (const float*)d_in[12];
  const float* fc_w   = (const float*)d_in[13];
  const float* fc_b   = (const float*)d_in[14];
  float* out = (float*)d_out;

  float* ws   = (float*)d_ws;
  int*   bar  = (int*)d_ws;
  float* hTx  = ws + OFF_HTX;
  float* oc   = ws + OFF_OC;
  float* hnew = ws + OFF_HNEW;
  float* whh  = ws + OFF_WHH;
  float* c0   = ws + OFF_C0;
  float* W2   = ws + OFF_W2;
  float* Mtmp = ws + OFF_MTMP;
  float* P1   = ws + OFF_P1;
  float* P2   = ws + OFF_P2;

  // zero: flag words + hTx buffer 0 (h=0, lu=0); slot caches (mem=0)
  hipMemsetAsync(d_ws, 0, (size_t)(OFF_HTX + HTXS) * sizeof(float), stream);
  hipMemsetAsync(hnew, 0, (size_t)(32*64*512 + 32*64*1536) * sizeof(float), stream);

  setup_kernel<<<2115, 512, 0, stream>>>(W_hm, fc2_w, W_um, W_hh, bias, fc2_b,
                                         W2, c0);

  // M_A = fc2_A@W_hh -> W2 cg 32..63 ; M_B = fc2_B@W_hh -> cg 64..95
  { dim3 g(4, 24);
    gemm_f32<<<g, 256, 0, stream>>>(fc2_w,                   W_hh, nullptr, Mtmp,
                                    512, 1536, 512, 512, 1536, 1536);
    trans_kernel<<<1536, 512, 0, stream>>>(Mtmp, W2, 32);
    gemm_f32<<<g, 256, 0, stream>>>(fc2_w + (size_t)512*512, W_hh, nullptr, Mtmp,
                                    512, 1536, 512, 512, 1536, 1536);
    trans_kernel<<<1536, 512, 0, stream>>>(Mtmp, W2, 64); }
  // P1 = x@W_ih + bias_ih ; P2 = x@W_im
  { dim3 g(32, 24);
    gemm_f32<<<g, 256, 0, stream>>>(x, W_ih, bias, P1, 4096, 1536, 512, 512, 1536, 1536); }
  { dim3 g(32, 8);
    gemm_f32<<<g, 256, 0, stream>>>(x, W_im, nullptr, P2, 4096, 512, 512, 512, 512, 512); }

  persist_kernel<<<NBLK, NTHR, 0, stream>>>(P1, P2, W2, oc, hTx, hnew, whh,
                                            c0, fc1_w, fc1_b, fc2_b, u_nois,
                                            length, fc_w, fc_b, out, bar);
}

// Round 10
// 2922.519 us; speedup vs baseline: 1.0844x; 1.0844x over previous
//
#include <hip/hip_runtime.h>
#include <hip/hip_bf16.h>
#include <math.h>

// T=128, B=32, D=512, H=512, N=64, A=32, TAU=1
#define NTHR  512
#define NBLK  224              // 32 BC blocks + 192 GEMM blocks
#define HTXS  20480            // hTx buffer stride: [32][640]

// ---- flag area (int offsets into d_ws) ----
// hflag[b]  = bar[b*32]            (BC b plain sc1-stores t+1 when h(t+1) out)
// wflag[g]  = bar[1024 + g*32]     (GEMM block g=cg*2+bg sc1-stores t+1)
#define OFF_HTX  8192                       // hTx_all: [129][32][640]
#define OFF_OC   (OFF_HTX + 129*HTXS)       // oc: [32][4608]
#define OFF_HNEW (OFF_OC + 32*4608)         // hnew_part: [32][64][512]
#define OFF_WHH  (OFF_HNEW + 32*64*512)     // whh_part: [32][64][1536]
#define OFF_C0   (OFF_WHH + 32*64*1536)     // c0: [1536]
#define OFF_WCAT (OFF_C0 + 1536)            // Wcat: [576][4608] row-major
#define OFF_P1   (OFF_WCAT + 576*4608)      // P1: [4096][1536]
#define OFF_P2   (OFF_P1 + 4096*1536)       // P2: [4096][512]
// end ≈ 72.1 MB

// sc1 (agent-scope): bypass per-XCD L2, coherent at LLC. Flags, oc, and hTx
// writes are sc1; hTx READS are normal cached loads (rotating buffers,
// write-once-then-read — validated r2/r3/r6/r7/r8 incl. graph replays).
__device__ __forceinline__ float cohLoad(const float* p) {
  return __hip_atomic_load(p, __ATOMIC_RELAXED, __HIP_MEMORY_SCOPE_AGENT);
}
__device__ __forceinline__ void cohStore(float* p, float v) {
  __hip_atomic_store(p, v, __ATOMIC_RELAXED, __HIP_MEMORY_SCOPE_AGENT);
}
__device__ __forceinline__ int cohLoadI(const int* p) {
  return __hip_atomic_load(p, __ATOMIC_RELAXED, __HIP_MEMORY_SCOPE_AGENT);
}
__device__ __forceinline__ void cohStoreI(int* p, int v) {
  __hip_atomic_store(p, v, __ATOMIC_RELAXED, __HIP_MEMORY_SCOPE_AGENT);
}

// ---------------------------------------------------------------------------
// Generic tiled fp32 GEMM (pre-pass only)
// ---------------------------------------------------------------------------
__global__ __launch_bounds__(256) void gemm_f32(
    const float* __restrict__ A, const float* __restrict__ B,
    const float* __restrict__ bias, float* __restrict__ C,
    int M, int N, int K, int lda, int ldb, int ldc)
{
  __shared__ float As[16][132];
  __shared__ float Bs[16][64];
  const int bm = blockIdx.x * 128, bn = blockIdx.y * 64;
  const int tid = threadIdx.x;
  const int tx = tid & 15, ty = tid >> 4;
  float acc[8][4];
  #pragma unroll
  for (int i = 0; i < 8; ++i)
    #pragma unroll
    for (int j = 0; j < 4; ++j) acc[i][j] = 0.f;

  for (int kt = 0; kt < K; kt += 16) {
    #pragma unroll
    for (int i = 0; i < 2; ++i) {
      int li = tid + i*256;
      int r = li >> 2, q = li & 3;
      float4 a4 = *(const float4*)(A + (size_t)(bm + r)*lda + kt + q*4);
      As[q*4+0][r] = a4.x; As[q*4+1][r] = a4.y;
      As[q*4+2][r] = a4.z; As[q*4+3][r] = a4.w;
    }
    {
      int k = tid >> 4, nq = tid & 15;
      *(float4*)(&Bs[k][nq*4]) = *(const float4*)(B + (size_t)(kt + k)*ldb + bn + nq*4);
    }
    __syncthreads();
    #pragma unroll
    for (int kk = 0; kk < 16; ++kk) {
      float av[8], bv[4];
      *(float4*)(av)   = *(const float4*)(&As[kk][ty*8]);
      *(float4*)(av+4) = *(const float4*)(&As[kk][ty*8+4]);
      *(float4*)(bv)   = *(const float4*)(&Bs[kk][tx*4]);
      #pragma unroll
      for (int i = 0; i < 8; ++i)
        #pragma unroll
        for (int j = 0; j < 4; ++j) acc[i][j] += av[i]*bv[j];
    }
    __syncthreads();
  }
  #pragma unroll
  for (int i = 0; i < 8; ++i) {
    int m = bm + ty*8 + i;
    #pragma unroll
    for (int j = 0; j < 4; ++j) {
      int n = bn + tx*4 + j;
      float v = acc[i][j];
      if (bias) v += bias[n];
      C[(size_t)m*ldc + n] = v;
    }
  }
}

// ---------------------------------------------------------------------------
// Setup: Wcat (row-major [576][4608]) static parts + c0.
// ---------------------------------------------------------------------------
__global__ __launch_bounds__(512) void setup_kernel(
    const float* __restrict__ W_hm, const float* __restrict__ fc2_w,
    const float* __restrict__ W_um, const float* __restrict__ W_hh,
    const float* __restrict__ bias, const float* __restrict__ fc2_b,
    float* __restrict__ Wcat, float* __restrict__ c0)
{
  const int idx = blockIdx.x * 512 + threadIdx.x;
  if (idx < 512*1536) {                       // rows 0:512, cols 0:1536
    int k = idx / 1536, c = idx % 1536;
    float v;
    if (c < 512)       v = W_hm[k*512 + c];
    else if (c < 1024) v = fc2_w[k*512 + (c-512)];
    else               v = fc2_w[(size_t)(512+k)*512 + (c-1024)];
    Wcat[(size_t)k*4608 + c] = v;
    return;
  }
  int i = idx - 512*1536;
  if (i < 64*4608) {                          // rows 512:576 (unused by K=512 GEMM)
    int k2 = i / 4608, c = i % 4608;
    Wcat[(size_t)(512+k2)*4608 + c] = (c < 512) ? W_um[k2*512 + c] : 0.f;
    return;
  }
  i -= 64*4608;
  if (i < 1536) {                             // c0 = fc2_b@W_hh + bias_hh
    float s = bias[1536 + i];
    for (int m = 0; m < 512; ++m) s += fc2_b[m] * W_hh[(size_t)m*1536 + i];
    c0[i] = s;
  }
}

// ---------------------------------------------------------------------------
// Persistent scan. Blocks 0..31: BC (batch b). Blocks 32..223: GEMM.
// GEMM block g=cg*2+bg: cols [cg*48,+48), batches [bg*16,+16), K=512 only
// (Wcat rows 512:576 are zero for all cols >=512; cols <512 are computed by
// BC locally and ignored here). Thread tile 4b x 3c over K-seg of 64.
// BC: computes th/fc1/argmax locally (overlaps GEMM round trip), then waits
// only its batch-half's 96 flags, reads oc[512:4608], gates, publishes h.
// ---------------------------------------------------------------------------
__global__ __launch_bounds__(NTHR, 1) void persist_kernel(
    const float* __restrict__ P1, const float* __restrict__ P2,
    const float* __restrict__ Wcat, float* __restrict__ oc,
    float* __restrict__ hTx_all, float* __restrict__ hnew_part,
    float* __restrict__ whh_part, const float* __restrict__ c0,
    const float* __restrict__ W_hm, const float* __restrict__ W_um,
    const float* __restrict__ fc1_w, const float* __restrict__ fc1_b,
    const float* __restrict__ fc2_b, const float* __restrict__ u_noise,
    const int* __restrict__ length, const float* __restrict__ fc_w,
    const float* __restrict__ fc_b, float* __restrict__ out,
    int* __restrict__ bar)
{
  __shared__ float smem[16448];   // GEMM: hxs[512*20]=10240 + red[8*776]; BC: scratch
  const int bid = blockIdx.x;
  const int tid = threadIdx.x;

  if (bid >= 32) {
    // ================= GEMM block =================
    const int gb  = bid - 32;            // 0..191
    const int cg  = gb >> 1;             // 0..95
    const int bg  = gb & 1;              // batch half
    const int colbase = cg * 48;
    const int s   = tid >> 6;            // K-seg 0..7 (64 rows)
    const int c   = (tid >> 2) & 15;     // col-triple 0..15
    const int bq  = tid & 3;             // batch-quad 0..3
    const int kbase = s * 64;
    float* hxs = smem;                   // [512][20] padded k-major
    float* red = smem + 10240;           // [8][776]

    for (int t = 0; t < 128; ++t) {
      // wait for my 16 batches' h(t)
      if (tid < 16) {
        while (cohLoadI(&bar[(bg*16 + tid)*32]) < t) __builtin_amdgcn_s_sleep(1);
      }
      __syncthreads();
      // stage + transpose: batch-contiguous global -> padded k-major LDS
      const float* hb = hTx_all + (size_t)t*HTXS + (bg*16)*640;
      #pragma unroll
      for (int c2 = 0; c2 < 16; ++c2) {
        int idx = c2*512 + tid;
        int bi = idx >> 9;               // 0..15
        int k  = idx & 511;
        hxs[k*20 + bi] = hb[bi*640 + k];
      }
      __syncthreads();
      // 4 batches x 3 cols register tile over K-seg of 64
      float acc[4][3];
      #pragma unroll
      for (int bi = 0; bi < 4; ++bi)
        #pragma unroll
        for (int cj = 0; cj < 3; ++cj) acc[bi][cj] = 0.f;
      const float* wp = Wcat + (size_t)kbase*4608 + colbase + c*3;
      const float* hp = hxs + kbase*20 + bq*4;
      #pragma unroll 4
      for (int kk = 0; kk < 64; ++kk) {
        float4 h4 = *(const float4*)(hp); hp += 20;
        float w0 = wp[0], w1 = wp[1], w2 = wp[2]; wp += 4608;
        acc[0][0] += h4.x*w0; acc[0][1] += h4.x*w1; acc[0][2] += h4.x*w2;
        acc[1][0] += h4.y*w0; acc[1][1] += h4.y*w1; acc[1][2] += h4.y*w2;
        acc[2][0] += h4.z*w0; acc[2][1] += h4.z*w1; acc[2][2] += h4.z*w2;
        acc[3][0] += h4.w*w0; acc[3][1] += h4.w*w1; acc[3][2] += h4.w*w2;
      }
      {
        float* rp = red + s*776 + (bq*4)*48 + c*3;
        #pragma unroll
        for (int bi = 0; bi < 4; ++bi) {
          rp[bi*48 + 0] = acc[bi][0];
          rp[bi*48 + 1] = acc[bi][1];
          rp[bi*48 + 2] = acc[bi][2];
        }
      }
      __syncthreads();
      // 8-seg reduce + sc1 store (full-line: 48 consecutive floats per batch)
      for (int i = tid; i < 768; i += NTHR) {
        float ssum = 0.f;
        #pragma unroll
        for (int w = 0; w < 8; ++w) ssum += red[w*776 + i];
        int b16 = i / 48, cc = i - b16*48;
        cohStore(&oc[(size_t)(bg*16 + b16)*4608 + colbase + cc], ssum);
      }
      __syncthreads();                   // drain sc1 stores (vmcnt 0)
      if (tid == 0) cohStoreI(&bar[1024 + gb*32], t + 1);
    }
  } else {
    // ================= BC block: batch b =================
    const int b = bid;
    const int bhalf = b >> 4;
    const int lenb = length[b];
    float hcur = 0.f;
    float usage_r = -99999.f;            // valid for tid<64
    int jprev = 0;                       // thread-0 only
    float* sh  = smem;                   // h(t): [0:512]
    float* slu = smem + 512;             // lu:   [512:576]
    float* sth = smem + 576;             // th:   [576:1088]
    float* sfc = smem + 1088;            // fc1 partials / out partials
    int* flg = (int*)(smem + 1600);
    const float c0r = c0[tid], c0z = c0[512 + tid], c0n = c0[1024 + tid];
    const float fc2bv = fc2_b[tid];
    const float f1b = (tid < 64) ? fc1_b[tid] : 0.f;
    const int n_ = tid & 63, kg_ = tid >> 6;
    const float* fw = fc1_w + (size_t)kg_*64*64 + n_;

    for (int t = 0; t < 128; ++t) {
      const int t32b = t*32 + b;
      sh[tid] = hcur;
      if (tid < 64) slu[tid] = 1.f / (1.f + expf(-usage_r));
      __syncthreads();
      // prefetch step inputs
      const float* p1p = P1 + (size_t)t32b*1536;
      float p1r = p1p[tid], p1z = p1p[512 + tid], p1n = p1p[1024 + tid];
      float p2v = P2[(size_t)t32b*512 + tid];
      float uval = (tid < 64) ? u_noise[(size_t)t32b*64 + tid] : 0.f;
      // ---- LOCAL th GEMV (overlaps GEMM blocks' round trip) ----
      float pre = p2v;
      {
        const float* wh = W_hm + tid;
        #pragma unroll 4
        for (int k4 = 0; k4 < 128; ++k4) {
          float4 hh = *(const float4*)(sh + k4*4);
          pre += hh.x * wh[0]; wh += 512;
          pre += hh.y * wh[0]; wh += 512;
          pre += hh.z * wh[0]; wh += 512;
          pre += hh.w * wh[0]; wh += 512;
        }
        const float* wu = W_um + tid;
        #pragma unroll
        for (int n4 = 0; n4 < 16; ++n4) {
          float4 uu = *(const float4*)(slu + n4*4);
          pre += uu.x * wu[0]; wu += 512;
          pre += uu.y * wu[0]; wu += 512;
          pre += uu.z * wu[0]; wu += 512;
          pre += uu.w * wu[0]; wu += 512;
        }
      }
      sth[tid] = tanhf(pre);
      __syncthreads();
      {                                  // fc1 partial dots
        float sdot = 0.f;
        #pragma unroll 8
        for (int k = 0; k < 64; ++k) sdot += sth[kg_*64 + k] * fw[(size_t)k*64];
        sfc[tid] = sdot;
      }
      __syncthreads();
      if (tid < 64) {                    // logits + Gumbel + wave argmax
        float l = f1b;
        #pragma unroll
        for (int kg = 0; kg < 8; ++kg) l += sfc[kg*64 + tid];
        l += -logf(1e-20f - logf(1e-20f + uval));
        float best = l; int idx = tid;
        #pragma unroll
        for (int off = 32; off >= 1; off >>= 1) {
          float ob = __shfl_xor(best, off);
          int   oi = __shfl_xor(idx,  off);
          if (ob > best || (ob == best && oi < idx)) { best = ob; idx = oi; }
        }
        if (tid == 0) {
          flg[0] = idx;
          flg[1] = (t < 64) ? t : jprev;
          jprev = idx;
        }
      }
      // ---- wait my batch-half's 96 GEMM flags ----
      if (tid < 96) {
        while (cohLoadI(&bar[1024 + (tid*2 + bhalf)*32]) < t + 1)
          __builtin_amdgcn_s_sleep(1);
      }
      __syncthreads();
      const int jj = flg[0], ss = flg[1];
      const float* ocb = oc + (size_t)b*4608;
      float vA   = cohLoad(ocb + 512  + tid);
      float vB   = cohLoad(ocb + 1024 + tid);
      float vAW0 = cohLoad(ocb + 1536 + tid);
      float vAW1 = cohLoad(ocb + 2048 + tid);
      float vAW2 = cohLoad(ocb + 2560 + tid);
      float vBW0 = cohLoad(ocb + 3072 + tid);
      float vBW1 = cohLoad(ocb + 3584 + tid);
      float vBW2 = cohLoad(ocb + 4096 + tid);
      float hnp, w0, w1, w2;
      if (jj == ss) { hnp = vA; w0 = vAW0; w1 = vAW1; w2 = vAW2; }
      else {
        hnp = hnew_part[(size_t)(b*64 + jj)*512 + tid];
        const float* wpp = whh_part + (size_t)(b*64 + jj)*1536;
        w0 = wpp[tid]; w1 = wpp[512 + tid]; w2 = wpp[1024 + tid];
      }
      float h_new = hnp + vB + fc2bv;
      float wh_r = w0 + vBW0 + c0r;
      float wh_z = w1 + vBW1 + c0z;
      float wh_n = w2 + vBW2 + c0n;
      float r  = 1.f / (1.f + expf(-(p1r + wh_r)));
      float z  = 1.f / (1.f + expf(-(p1z + wh_z)));
      float nn = tanhf(p1n + r*wh_n);
      float h1 = (1.f - z)*nn + z*h_new;
      if (t >= lenb) h1 = hcur;
      hcur = h1;
      // publish h(t+1): batch-contiguous, full-line sc1 stores
      float* hw = hTx_all + (size_t)(t + 1)*HTXS + b*640;
      cohStore(&hw[tid], h1);
      if (tid < 64)
        usage_r = (usage_r - 1.f) * (tid == jj ? 0.f : 1.f);
      sh[tid] = h1;                      // for out projection
      __syncthreads();                   // drain sc1 stores
      if (tid == 0) cohStoreI(&bar[b*32], t + 1);
      // ---- off critical path: slot caches + output projection ----
      hnew_part[(size_t)(b*64 + ss)*512 + tid] = vA;
      float* wps = whh_part + (size_t)(b*64 + ss)*1536;
      wps[tid] = vAW0; wps[512 + tid] = vAW1; wps[1024 + tid] = vAW2;
      {
        int a = tid & 31, jg = tid >> 5;
        float sp = 0.f;
        #pragma unroll 8
        for (int jx = 0; jx < 32; ++jx)
          sp += sh[jg*32 + jx] * fc_w[(size_t)(jg*32 + jx)*32 + a];
        sfc[tid] = sp;
      }
      __syncthreads();
      if (tid < 32) {
        float s2 = fc_b[tid];
        #pragma unroll
        for (int jg = 0; jg < 16; ++jg) s2 += sfc[jg*32 + tid];
        out[(size_t)t32b*32 + tid] = s2;
      }
    }
  }
}

// ---------------------------------------------------------------------------
extern "C" void kernel_launch(void* const* d_in, const int* in_sizes, int n_in,
                              void* d_out, int out_size, void* d_ws, size_t ws_size,
                              hipStream_t stream)
{
  const float* x      = (const float*)d_in[0];
  const int*   length = (const int*)  d_in[1];
  const float* u_nois = (const float*)d_in[2];
  const float* W_ih   = (const float*)d_in[3];
  const float* W_hh   = (const float*)d_in[4];
  const float* bias   = (const float*)d_in[5];
  const float* W_im   = (const float*)d_in[6];
  const float* W_hm   = (const float*)d_in[7];
  const float* W_um   = (const float*)d_in[8];
  const float* fc1_w  = (const float*)d_in[9];
  const float* fc1_b  = (const float*)d_in[10];
  const float* fc2_w  = (const float*)d_in[11];
  const float* fc2_b  = (const float*)d_in[12];
  const float* fc_w   = (const float*)d_in[13];
  const float* fc_b   = (const float*)d_in[14];
  float* out = (float*)d_out;

  float* ws   = (float*)d_ws;
  int*   bar  = (int*)d_ws;
  float* hTx  = ws + OFF_HTX;
  float* oc   = ws + OFF_OC;
  float* hnew = ws + OFF_HNEW;
  float* whh  = ws + OFF_WHH;
  float* c0   = ws + OFF_C0;
  float* Wcat = ws + OFF_WCAT;
  float* P1   = ws + OFF_P1;
  float* P2   = ws + OFF_P2;

  // zero: flag words + hTx buffer 0 (h=0); slot caches (mem=0)
  hipMemsetAsync(d_ws, 0, (size_t)(OFF_HTX + HTXS) * sizeof(float), stream);
  hipMemsetAsync(hnew, 0, (size_t)(32*64*512 + 32*64*1536) * sizeof(float), stream);

  setup_kernel<<<2115, 512, 0, stream>>>(W_hm, fc2_w, W_um, W_hh, bias, fc2_b,
                                         Wcat, c0);

  // M_A = fc2_A@W_hh -> Wcat cols 1536:3072 ; M_B = fc2_B@W_hh -> 3072:4608
  { dim3 g(4, 24);
    gemm_f32<<<g, 256, 0, stream>>>(fc2_w,                   W_hh, nullptr, Wcat + 1536,
                                    512, 1536, 512, 512, 1536, 4608);
    gemm_f32<<<g, 256, 0, stream>>>(fc2_w + (size_t)512*512, W_hh, nullptr, Wcat + 3072,
                                    512, 1536, 512, 512, 1536, 4608); }
  // P1 = x@W_ih + bias_ih ; P2 = x@W_im
  { dim3 g(32, 24);
    gemm_f32<<<g, 256, 0, stream>>>(x, W_ih, bias, P1, 4096, 1536, 512, 512, 1536, 1536); }
  { dim3 g(32, 8);
    gemm_f32<<<g, 256, 0, stream>>>(x, W_im, nullptr, P2, 4096, 512, 512, 512, 512, 512); }

  persist_kernel<<<NBLK, NTHR, 0, stream>>>(P1, P2, Wcat, oc, hTx, hnew, whh,
                                            c0, W_hm, W_um, fc1_w, fc1_b, fc2_b,
                                            u_nois, length, fc_w, fc_b, out, bar);
}

// Round 11
// 2621.258 us; speedup vs baseline: 1.2090x; 1.1149x over previous
//
#include <hip/hip_runtime.h>
#include <hip/hip_bf16.h>
#include <math.h>

// T=128, B=32, D=512, H=512, N=64, A=32, TAU=1
#define NTHR  512
#define NBLK  224              // 32 BC blocks + 192 GEMM blocks
#define HTXS  19456            // hTx buffer stride (2*9216 + pad)

// ---- flag area (int offsets into d_ws), DENSE packing ----
// hflag[b] = bar[b]        (32 ints, 2 lines; BC b sc1-stores t+1)
// wflag[g] = bar[64 + g]   (192 ints; GEMM block g=cg*2+bg sc1-stores t+1)
//   g<64 ("early") <=> cg<32 <=> cols [0,1536) fp32 K=576
//   g>=64 ("late")  <=> cg>=32 <=> cols [1536,4608) bf16 K=512
#define OFF_HTX  8192                       // hTx_all: [129][2][576][16]
#define OFF_OC   (OFF_HTX + 129*HTXS)       // oc: [32][4608]
#define OFF_HNEW (OFF_OC + 32*4608)         // hnew_part: [32][64][512]
#define OFF_WHH  (OFF_HNEW + 32*64*512)     // whh_part: [32][64][1536]
#define OFF_C0   (OFF_WHH + 32*64*1536)     // c0: [1536]
#define OFF_WCAT (OFF_C0 + 1536)            // Wcat: [576][4608] fp32 row-major
#define OFF_WB16 (OFF_WCAT + 576*4608)      // Wb16: [512][3072] bf16 (ushort)
#define OFF_P1   (OFF_WB16 + 512*1536)      // P1: [4096][1536]  (Wb16 = 786432 floats of space)
#define OFF_P2   (OFF_P1 + 4096*1536)       // P2: [4096][512]
// end ≈ 75.1 MB (< 76.5 MB known-good)

// sc1 (agent-scope): bypass per-XCD L2, coherent at LLC. Flags, oc, hTx
// writes are sc1; hTx READS are normal cached loads (rotating buffers).
__device__ __forceinline__ float cohLoad(const float* p) {
  return __hip_atomic_load(p, __ATOMIC_RELAXED, __HIP_MEMORY_SCOPE_AGENT);
}
__device__ __forceinline__ void cohStore(float* p, float v) {
  __hip_atomic_store(p, v, __ATOMIC_RELAXED, __HIP_MEMORY_SCOPE_AGENT);
}
__device__ __forceinline__ int cohLoadI(const int* p) {
  return __hip_atomic_load(p, __ATOMIC_RELAXED, __HIP_MEMORY_SCOPE_AGENT);
}
__device__ __forceinline__ void cohStoreI(int* p, int v) {
  __hip_atomic_store(p, v, __ATOMIC_RELAXED, __HIP_MEMORY_SCOPE_AGENT);
}
__device__ __forceinline__ float bf2f(unsigned short u) {
  return __uint_as_float(((unsigned int)u) << 16);
}

// ---------------------------------------------------------------------------
// Generic tiled fp32 GEMM (pre-pass only)
// ---------------------------------------------------------------------------
__global__ __launch_bounds__(256) void gemm_f32(
    const float* __restrict__ A, const float* __restrict__ B,
    const float* __restrict__ bias, float* __restrict__ C,
    int M, int N, int K, int lda, int ldb, int ldc)
{
  __shared__ float As[16][132];
  __shared__ float Bs[16][64];
  const int bm = blockIdx.x * 128, bn = blockIdx.y * 64;
  const int tid = threadIdx.x;
  const int tx = tid & 15, ty = tid >> 4;
  float acc[8][4];
  #pragma unroll
  for (int i = 0; i < 8; ++i)
    #pragma unroll
    for (int j = 0; j < 4; ++j) acc[i][j] = 0.f;

  for (int kt = 0; kt < K; kt += 16) {
    #pragma unroll
    for (int i = 0; i < 2; ++i) {
      int li = tid + i*256;
      int r = li >> 2, q = li & 3;
      float4 a4 = *(const float4*)(A + (size_t)(bm + r)*lda + kt + q*4);
      As[q*4+0][r] = a4.x; As[q*4+1][r] = a4.y;
      As[q*4+2][r] = a4.z; As[q*4+3][r] = a4.w;
    }
    {
      int k = tid >> 4, nq = tid & 15;
      *(float4*)(&Bs[k][nq*4]) = *(const float4*)(B + (size_t)(kt + k)*ldb + bn + nq*4);
    }
    __syncthreads();
    #pragma unroll
    for (int kk = 0; kk < 16; ++kk) {
      float av[8], bv[4];
      *(float4*)(av)   = *(const float4*)(&As[kk][ty*8]);
      *(float4*)(av+4) = *(const float4*)(&As[kk][ty*8+4]);
      *(float4*)(bv)   = *(const float4*)(&Bs[kk][tx*4]);
      #pragma unroll
      for (int i = 0; i < 8; ++i)
        #pragma unroll
        for (int j = 0; j < 4; ++j) acc[i][j] += av[i]*bv[j];
    }
    __syncthreads();
  }
  #pragma unroll
  for (int i = 0; i < 8; ++i) {
    int m = bm + ty*8 + i;
    #pragma unroll
    for (int j = 0; j < 4; ++j) {
      int n = bn + tx*4 + j;
      float v = acc[i][j];
      if (bias) v += bias[n];
      C[(size_t)m*ldc + n] = v;
    }
  }
}

// ---------------------------------------------------------------------------
// Setup: Wcat (row-major [576][4608]) static parts + c0.
// ---------------------------------------------------------------------------
__global__ __launch_bounds__(512) void setup_kernel(
    const float* __restrict__ W_hm, const float* __restrict__ fc2_w,
    const float* __restrict__ W_um, const float* __restrict__ W_hh,
    const float* __restrict__ bias, const float* __restrict__ fc2_b,
    float* __restrict__ Wcat, float* __restrict__ c0)
{
  const int idx = blockIdx.x * 512 + threadIdx.x;
  if (idx < 512*1536) {                       // rows 0:512, cols 0:1536
    int k = idx / 1536, c = idx % 1536;
    float v;
    if (c < 512)       v = W_hm[k*512 + c];
    else if (c < 1024) v = fc2_w[k*512 + (c-512)];
    else               v = fc2_w[(size_t)(512+k)*512 + (c-1024)];
    Wcat[(size_t)k*4608 + c] = v;
    return;
  }
  int i = idx - 512*1536;
  if (i < 64*4608) {                          // rows 512:576
    int k2 = i / 4608, c = i % 4608;
    Wcat[(size_t)(512+k2)*4608 + c] = (c < 512) ? W_um[k2*512 + c] : 0.f;
    return;
  }
  i -= 64*4608;
  if (i < 1536) {                             // c0 = fc2_b@W_hh + bias_hh
    float s = bias[1536 + i];
    for (int m = 0; m < 512; ++m) s += fc2_b[m] * W_hh[(size_t)m*1536 + i];
    c0[i] = s;
  }
}

// Wb16[k][3072] = bf16(Wcat[k][1536+c]), k<512 — runs after M_A/M_B GEMMs.
__global__ __launch_bounds__(512) void cvt_kernel(
    const float* __restrict__ Wcat, unsigned short* __restrict__ Wb16)
{
  const int idx = blockIdx.x * 512 + threadIdx.x;   // 512*3072
  const int k = idx / 3072, c = idx % 3072;
  __hip_bfloat16 h = __float2bfloat16(Wcat[(size_t)k*4608 + 1536 + c]);
  Wb16[idx] = *(unsigned short*)&h;
}

// ---------------------------------------------------------------------------
// Persistent scan. Blocks 0..31: BC (batch). Blocks 32..223: GEMM.
// GEMM block g=cg*2+bg: cols [cg*48,+48), batches [bg*16,+16).
//   cg<32:  fp32 Wcat, K=576 (th/vA/vB path — argmax-sensitive, full precision)
//   cg>=32: bf16 Wb16, K=512 (gate path; rows 512:576 structurally zero)
// Thread tile 4b x 3c per K-seg. Dense flags; one poll line per wave.
// ---------------------------------------------------------------------------
__global__ __launch_bounds__(NTHR, 1) void persist_kernel(
    const float* __restrict__ P1, const float* __restrict__ P2,
    const float* __restrict__ Wcat, const unsigned short* __restrict__ Wb16,
    float* __restrict__ oc, float* __restrict__ hTx_all,
    float* __restrict__ hnew_part, float* __restrict__ whh_part,
    const float* __restrict__ c0, const float* __restrict__ fc1_w,
    const float* __restrict__ fc1_b, const float* __restrict__ fc2_b,
    const float* __restrict__ u_noise, const int* __restrict__ length,
    const float* __restrict__ fc_w, const float* __restrict__ fc_b,
    float* __restrict__ out, int* __restrict__ bar)
{
  __shared__ float smem[15424];    // GEMM: hxs[9216] + red[8*776]; BC: scratch
  const int bid = blockIdx.x;
  const int tid = threadIdx.x;

  if (bid >= 32) {
    // ================= GEMM block =================
    const int gb  = bid - 32;            // 0..191
    const int cg  = gb >> 1;             // 0..95
    const int bg  = gb & 1;              // batch half
    const bool late = (cg >= 32);
    const int colbase = cg * 48;
    const int s   = tid >> 6;            // K-seg 0..7
    const int c   = (tid >> 2) & 15;     // col-triple 0..15
    const int bq  = tid & 3;             // batch-quad 0..3
    const int seg = late ? 64 : 72;
    const int kbase = s * seg;
    const int stageN = late ? 2048 : 2304;   // float4 count (8192 / 9216 floats)
    float* hxs = smem;                   // [576][16] k-major (this batch-half)
    float* red = smem + 9216;            // [8][776]

    for (int t = 0; t < 128; ++t) {
      // wait for my 16 batches' h(t): dense line -> 1 transaction per poll
      if (tid < 16) {
        while (cohLoadI(&bar[bg*16 + tid]) < t) __builtin_amdgcn_s_sleep(1);
      }
      __syncthreads();
      // stage hx half (k-major, rows 0:512 first -> late blocks load less)
      const float* hsrc = hTx_all + (size_t)t*HTXS + bg*9216;
      for (int i = tid; i < stageN; i += NTHR)
        *(float4*)(hxs + i*4) = *(const float4*)(hsrc + i*4);
      __syncthreads();
      // 4 batches x 3 cols register tile
      float acc[4][3];
      #pragma unroll
      for (int bi = 0; bi < 4; ++bi)
        #pragma unroll
        for (int cj = 0; cj < 3; ++cj) acc[bi][cj] = 0.f;
      const float* hp = hxs + kbase*16 + bq*4;
      if (!late) {
        const float* wp = Wcat + (size_t)kbase*4608 + colbase + c*3;
        #pragma unroll 4
        for (int kk = 0; kk < 72; ++kk) {
          float4 h4 = *(const float4*)(hp); hp += 16;
          float w0 = wp[0], w1 = wp[1], w2 = wp[2]; wp += 4608;
          acc[0][0] += h4.x*w0; acc[0][1] += h4.x*w1; acc[0][2] += h4.x*w2;
          acc[1][0] += h4.y*w0; acc[1][1] += h4.y*w1; acc[1][2] += h4.y*w2;
          acc[2][0] += h4.z*w0; acc[2][1] += h4.z*w1; acc[2][2] += h4.z*w2;
          acc[3][0] += h4.w*w0; acc[3][1] += h4.w*w1; acc[3][2] += h4.w*w2;
        }
      } else {
        const unsigned short* wp = Wb16 + (size_t)kbase*3072 + (colbase - 1536) + c*3;
        #pragma unroll 4
        for (int kk = 0; kk < 64; ++kk) {
          float4 h4 = *(const float4*)(hp); hp += 16;
          float w0 = bf2f(wp[0]), w1 = bf2f(wp[1]), w2 = bf2f(wp[2]); wp += 3072;
          acc[0][0] += h4.x*w0; acc[0][1] += h4.x*w1; acc[0][2] += h4.x*w2;
          acc[1][0] += h4.y*w0; acc[1][1] += h4.y*w1; acc[1][2] += h4.y*w2;
          acc[2][0] += h4.z*w0; acc[2][1] += h4.z*w1; acc[2][2] += h4.z*w2;
          acc[3][0] += h4.w*w0; acc[3][1] += h4.w*w1; acc[3][2] += h4.w*w2;
        }
      }
      {
        float* rp = red + s*776 + (bq*4)*48 + c*3;
        #pragma unroll
        for (int bi = 0; bi < 4; ++bi) {
          rp[bi*48 + 0] = acc[bi][0];
          rp[bi*48 + 1] = acc[bi][1];
          rp[bi*48 + 2] = acc[bi][2];
        }
      }
      __syncthreads();
      // 8-seg reduce + sc1 store to oc
      for (int i = tid; i < 768; i += NTHR) {
        float ssum = 0.f;
        #pragma unroll
        for (int w = 0; w < 8; ++w) ssum += red[w*776 + i];
        int b16 = i / 48, cc = i - b16*48;
        cohStore(&oc[(size_t)(bg*16 + b16)*4608 + colbase + cc], ssum);
      }
      __syncthreads();                   // drain sc1 stores (vmcnt 0)
      if (tid == 0) cohStoreI(&bar[64 + gb], t + 1);
    }
  } else {
    // ================= BC block: batch b =================
    const int b = bid;
    const int lenb = length[b];
    float hcur = 0.f;
    float usage_r = -99999.f;            // valid for tid<64
    int jprev = 0;                       // thread-0 only
    int* flg = (int*)(smem + 1100);
    const float c0r = c0[tid], c0z = c0[512 + tid], c0n = c0[1024 + tid];
    const float fc2bv = fc2_b[tid];
    const float f1b = (tid < 64) ? fc1_b[tid] : 0.f;
    const int n_ = tid & 63, kg_ = tid >> 6;
    const float* fw = fc1_w + (size_t)kg_*64*64 + n_;

    for (int t = 0; t < 128; ++t) {
      const int t32b = t*32 + b;
      // prefetch step inputs (independent of flags)
      const float* p1p = P1 + (size_t)t32b*1536;
      float p1r = p1p[tid], p1z = p1p[512 + tid], p1n = p1p[1024 + tid];
      float p2v = P2[(size_t)t32b*512 + tid];
      float uval = (tid < 64) ? u_noise[(size_t)t32b*64 + tid] : 0.f;
      // ---- wait EARLY blocks (g 0..63), dense: wave 0 polls 4 lines ----
      if (tid < 64) {
        while (cohLoadI(&bar[64 + tid]) < t + 1) __builtin_amdgcn_s_sleep(1);
      }
      __syncthreads();
      const float* ocb = oc + (size_t)b*4608;
      float oct = cohLoad(ocb + tid);
      float vA  = cohLoad(ocb + 512  + tid);
      float vB  = cohLoad(ocb + 1024 + tid);
      smem[tid] = tanhf(p2v + oct);      // th
      __syncthreads();
      {                                  // fc1 partial dots
        float sdot = 0.f;
        #pragma unroll 8
        for (int k = 0; k < 64; ++k) sdot += smem[kg_*64 + k] * fw[(size_t)k*64];
        smem[512 + tid] = sdot;
      }
      __syncthreads();
      if (tid < 64) {                    // logits + Gumbel + wave argmax
        float l = f1b;
        #pragma unroll
        for (int kg = 0; kg < 8; ++kg) l += smem[512 + kg*64 + tid];
        l += -logf(1e-20f - logf(1e-20f + uval));
        float best = l; int idx = tid;
        #pragma unroll
        for (int off = 32; off >= 1; off >>= 1) {
          float ob = __shfl_xor(best, off);
          int   oi = __shfl_xor(idx,  off);
          if (ob > best || (ob == best && oi < idx)) { best = ob; idx = oi; }
        }
        if (tid == 0) {
          flg[0] = idx;
          flg[1] = (t < 64) ? t : jprev;
          jprev = idx;
        }
      }
      // ---- wait LATE blocks (g 64..191), dense: 2 waves poll 8 lines ----
      if (tid < 128) {
        while (cohLoadI(&bar[128 + tid]) < t + 1) __builtin_amdgcn_s_sleep(1);
      }
      __syncthreads();
      const int jj = flg[0], ss = flg[1];
      float vAW0 = cohLoad(ocb + 1536 + tid);
      float vAW1 = cohLoad(ocb + 2048 + tid);
      float vAW2 = cohLoad(ocb + 2560 + tid);
      float vBW0 = cohLoad(ocb + 3072 + tid);
      float vBW1 = cohLoad(ocb + 3584 + tid);
      float vBW2 = cohLoad(ocb + 4096 + tid);
      float hnp, w0, w1, w2;
      if (jj == ss) { hnp = vA; w0 = vAW0; w1 = vAW1; w2 = vAW2; }
      else {
        hnp = hnew_part[(size_t)(b*64 + jj)*512 + tid];
        const float* wpp = whh_part + (size_t)(b*64 + jj)*1536;
        w0 = wpp[tid]; w1 = wpp[512 + tid]; w2 = wpp[1024 + tid];
      }
      float h_new = hnp + vB + fc2bv;
      float wh_r = w0 + vBW0 + c0r;
      float wh_z = w1 + vBW1 + c0z;
      float wh_n = w2 + vBW2 + c0n;
      float r  = 1.f / (1.f + expf(-(p1r + wh_r)));
      float z  = 1.f / (1.f + expf(-(p1z + wh_z)));
      float nn = tanhf(p1n + r*wh_n);
      float h1 = (1.f - z)*nn + z*h_new;
      if (t >= lenb) h1 = hcur;
      hcur = h1;
      // publish h(t+1)+lu via sc1 (k-major [576][16], half b>>4)
      float* hw = hTx_all + (size_t)(t + 1)*HTXS + (b >> 4)*9216;
      cohStore(&hw[tid*16 + (b & 15)], h1);
      if (tid < 64) {
        float un = (usage_r - 1.f) * (tid == jj ? 0.f : 1.f);
        usage_r = un;
        cohStore(&hw[(512 + tid)*16 + (b & 15)], 1.f / (1.f + expf(-un)));
      }
      smem[tid] = h1;                    // for out projection below
      __syncthreads();                   // drain sc1 stores
      if (tid == 0) cohStoreI(&bar[b], t + 1);
      // ---- off critical path: slot caches + output projection ----
      hnew_part[(size_t)(b*64 + ss)*512 + tid] = vA;
      float* wps = whh_part + (size_t)(b*64 + ss)*1536;
      wps[tid] = vAW0; wps[512 + tid] = vAW1; wps[1024 + tid] = vAW2;
      {
        int a = tid & 31, jg = tid >> 5;
        float sp = 0.f;
        #pragma unroll 8
        for (int jx = 0; jx < 32; ++jx)
          sp += smem[jg*32 + jx] * fc_w[(size_t)(jg*32 + jx)*32 + a];
        smem[512 + tid] = sp;
      }
      __syncthreads();
      if (tid < 32) {
        float s2 = fc_b[tid];
        #pragma unroll
        for (int jg = 0; jg < 16; ++jg) s2 += smem[512 + jg*32 + tid];
        out[(size_t)t32b*32 + tid] = s2;
      }
    }
  }
}

// ---------------------------------------------------------------------------
extern "C" void kernel_launch(void* const* d_in, const int* in_sizes, int n_in,
                              void* d_out, int out_size, void* d_ws, size_t ws_size,
                              hipStream_t stream)
{
  const float* x      = (const float*)d_in[0];
  const int*   length = (const int*)  d_in[1];
  const float* u_nois = (const float*)d_in[2];
  const float* W_ih   = (const float*)d_in[3];
  const float* W_hh   = (const float*)d_in[4];
  const float* bias   = (const float*)d_in[5];
  const float* W_im   = (const float*)d_in[6];
  const float* W_hm   = (const float*)d_in[7];
  const float* W_um   = (const float*)d_in[8];
  const float* fc1_w  = (const float*)d_in[9];
  const float* fc1_b  = (const float*)d_in[10];
  const float* fc2_w  = (const float*)d_in[11];
  const float* fc2_b  = (const float*)d_in[12];
  const float* fc_w   = (const float*)d_in[13];
  const float* fc_b   = (const float*)d_in[14];
  float* out = (float*)d_out;

  float* ws   = (float*)d_ws;
  int*   bar  = (int*)d_ws;
  float* hTx  = ws + OFF_HTX;
  float* oc   = ws + OFF_OC;
  float* hnew = ws + OFF_HNEW;
  float* whh  = ws + OFF_WHH;
  float* c0   = ws + OFF_C0;
  float* Wcat = ws + OFF_WCAT;
  unsigned short* Wb16 = (unsigned short*)(ws + OFF_WB16);
  float* P1   = ws + OFF_P1;
  float* P2   = ws + OFF_P2;

  // zero: flag words + hTx buffer 0 (h=0, lu=0); slot caches (mem=0)
  hipMemsetAsync(d_ws, 0, (size_t)(OFF_HTX + HTXS) * sizeof(float), stream);
  hipMemsetAsync(hnew, 0, (size_t)(32*64*512 + 32*64*1536) * sizeof(float), stream);

  setup_kernel<<<2115, 512, 0, stream>>>(W_hm, fc2_w, W_um, W_hh, bias, fc2_b,
                                         Wcat, c0);

  // M_A = fc2_A@W_hh -> Wcat cols 1536:3072 ; M_B = fc2_B@W_hh -> 3072:4608
  { dim3 g(4, 24);
    gemm_f32<<<g, 256, 0, stream>>>(fc2_w,                   W_hh, nullptr, Wcat + 1536,
                                    512, 1536, 512, 512, 1536, 4608);
    gemm_f32<<<g, 256, 0, stream>>>(fc2_w + (size_t)512*512, W_hh, nullptr, Wcat + 3072,
                                    512, 1536, 512, 512, 1536, 4608); }
  // bf16 compaction of the gate-path composite weights
  cvt_kernel<<<3072, 512, 0, stream>>>(Wcat, Wb16);
  // P1 = x@W_ih + bias_ih ; P2 = x@W_im
  { dim3 g(32, 24);
    gemm_f32<<<g, 256, 0, stream>>>(x, W_ih, bias, P1, 4096, 1536, 512, 512, 1536, 1536); }
  { dim3 g(32, 8);
    gemm_f32<<<g, 256, 0, stream>>>(x, W_im, nullptr, P2, 4096, 512, 512, 512, 512, 512); }

  persist_kernel<<<NBLK, NTHR, 0, stream>>>(P1, P2, Wcat, Wb16, oc, hTx, hnew,
                                            whh, c0, fc1_w, fc1_b, fc2_b,
                                            u_nois, length, fc_w, fc_b, out, bar);
}

// Round 12
// 2355.472 us; speedup vs baseline: 1.3454x; 1.1128x over previous
//
#include <hip/hip_runtime.h>
#include <hip/hip_bf16.h>
#include <math.h>

// T=128, B=32, D=512, H=512, N=64, A=32, TAU=1
#define NTHR  512
#define NBLK  224              // 32 BC blocks + 192 GEMM blocks
#define HTXS  19456            // hTx buffer stride (2*9216 + pad)

// ---- flag area (int offsets into d_ws), LINE-SPACED (r8-proven) ----
// hflag[b] = bar[b*32]           (BC b sc1-stores t+1; own 128B line)
// wflag[g] = bar[1024 + g*32]    (GEMM block g=cg*2+bg sc1-stores t+1)
//   g<64 ("early") <=> cg<32 <=> cols [0,1536) fp32 K=576
//   g>=64 ("late") <=> cg>=32 <=> cols [1536,4608) bf16 K=512
#define OFF_HTX  8192                       // hTx_all: [129][2][576][16]
#define OFF_OC   (OFF_HTX + 129*HTXS)       // oc: [32][4608]
#define OFF_HNEW (OFF_OC + 32*4608)         // hnew_part: [32][64][512]
#define OFF_WHH  (OFF_HNEW + 32*64*512)     // whh_part: [32][64][1536]
#define OFF_C0   (OFF_WHH + 32*64*1536)     // c0: [1536]
#define OFF_WCAT (OFF_C0 + 1536)            // Wcat: [576][4608] fp32 row-major
#define OFF_WB16 (OFF_WCAT + 576*4608)      // Wb16: [512][3072] bf16 (ushort)
#define OFF_P1   (OFF_WB16 + 512*1536)      // P1: [4096][1536]
#define OFF_P2   (OFF_P1 + 4096*1536)       // P2: [4096][512]
// end ≈ 75.1 MB (< 76.5 MB known-good)

// sc1 (agent-scope): bypass per-XCD L2, coherent at LLC. Flags, oc, hTx
// writes are sc1; hTx READS are normal cached loads (rotating buffers).
__device__ __forceinline__ float cohLoad(const float* p) {
  return __hip_atomic_load(p, __ATOMIC_RELAXED, __HIP_MEMORY_SCOPE_AGENT);
}
__device__ __forceinline__ void cohStore(float* p, float v) {
  __hip_atomic_store(p, v, __ATOMIC_RELAXED, __HIP_MEMORY_SCOPE_AGENT);
}
__device__ __forceinline__ int cohLoadI(const int* p) {
  return __hip_atomic_load(p, __ATOMIC_RELAXED, __HIP_MEMORY_SCOPE_AGENT);
}
__device__ __forceinline__ void cohStoreI(int* p, int v) {
  __hip_atomic_store(p, v, __ATOMIC_RELAXED, __HIP_MEMORY_SCOPE_AGENT);
}
__device__ __forceinline__ float bf2f(unsigned short u) {
  return __uint_as_float(((unsigned int)u) << 16);
}

// ---------------------------------------------------------------------------
// Generic tiled fp32 GEMM (pre-pass only)
// ---------------------------------------------------------------------------
__global__ __launch_bounds__(256) void gemm_f32(
    const float* __restrict__ A, const float* __restrict__ B,
    const float* __restrict__ bias, float* __restrict__ C,
    int M, int N, int K, int lda, int ldb, int ldc)
{
  __shared__ float As[16][132];
  __shared__ float Bs[16][64];
  const int bm = blockIdx.x * 128, bn = blockIdx.y * 64;
  const int tid = threadIdx.x;
  const int tx = tid & 15, ty = tid >> 4;
  float acc[8][4];
  #pragma unroll
  for (int i = 0; i < 8; ++i)
    #pragma unroll
    for (int j = 0; j < 4; ++j) acc[i][j] = 0.f;

  for (int kt = 0; kt < K; kt += 16) {
    #pragma unroll
    for (int i = 0; i < 2; ++i) {
      int li = tid + i*256;
      int r = li >> 2, q = li & 3;
      float4 a4 = *(const float4*)(A + (size_t)(bm + r)*lda + kt + q*4);
      As[q*4+0][r] = a4.x; As[q*4+1][r] = a4.y;
      As[q*4+2][r] = a4.z; As[q*4+3][r] = a4.w;
    }
    {
      int k = tid >> 4, nq = tid & 15;
      *(float4*)(&Bs[k][nq*4]) = *(const float4*)(B + (size_t)(kt + k)*ldb + bn + nq*4);
    }
    __syncthreads();
    #pragma unroll
    for (int kk = 0; kk < 16; ++kk) {
      float av[8], bv[4];
      *(float4*)(av)   = *(const float4*)(&As[kk][ty*8]);
      *(float4*)(av+4) = *(const float4*)(&As[kk][ty*8+4]);
      *(float4*)(bv)   = *(const float4*)(&Bs[kk][tx*4]);
      #pragma unroll
      for (int i = 0; i < 8; ++i)
        #pragma unroll
        for (int j = 0; j < 4; ++j) acc[i][j] += av[i]*bv[j];
    }
    __syncthreads();
  }
  #pragma unroll
  for (int i = 0; i < 8; ++i) {
    int m = bm + ty*8 + i;
    #pragma unroll
    for (int j = 0; j < 4; ++j) {
      int n = bn + tx*4 + j;
      float v = acc[i][j];
      if (bias) v += bias[n];
      C[(size_t)m*ldc + n] = v;
    }
  }
}

// ---------------------------------------------------------------------------
// Setup: Wcat (row-major [576][4608]) static parts + c0.
// ---------------------------------------------------------------------------
__global__ __launch_bounds__(512) void setup_kernel(
    const float* __restrict__ W_hm, const float* __restrict__ fc2_w,
    const float* __restrict__ W_um, const float* __restrict__ W_hh,
    const float* __restrict__ bias, const float* __restrict__ fc2_b,
    float* __restrict__ Wcat, float* __restrict__ c0)
{
  const int idx = blockIdx.x * 512 + threadIdx.x;
  if (idx < 512*1536) {                       // rows 0:512, cols 0:1536
    int k = idx / 1536, c = idx % 1536;
    float v;
    if (c < 512)       v = W_hm[k*512 + c];
    else if (c < 1024) v = fc2_w[k*512 + (c-512)];
    else               v = fc2_w[(size_t)(512+k)*512 + (c-1024)];
    Wcat[(size_t)k*4608 + c] = v;
    return;
  }
  int i = idx - 512*1536;
  if (i < 64*4608) {                          // rows 512:576
    int k2 = i / 4608, c = i % 4608;
    Wcat[(size_t)(512+k2)*4608 + c] = (c < 512) ? W_um[k2*512 + c] : 0.f;
    return;
  }
  i -= 64*4608;
  if (i < 1536) {                             // c0 = fc2_b@W_hh + bias_hh
    float s = bias[1536 + i];
    for (int m = 0; m < 512; ++m) s += fc2_b[m] * W_hh[(size_t)m*1536 + i];
    c0[i] = s;
  }
}

// Wb16[k][3072] = bf16(Wcat[k][1536+c]), k<512 — runs after M_A/M_B GEMMs.
__global__ __launch_bounds__(512) void cvt_kernel(
    const float* __restrict__ Wcat, unsigned short* __restrict__ Wb16)
{
  const int idx = blockIdx.x * 512 + threadIdx.x;   // 512*3072
  const int k = idx / 3072, c = idx % 3072;
  __hip_bfloat16 h = __float2bfloat16(Wcat[(size_t)k*4608 + 1536 + c]);
  Wb16[idx] = *(unsigned short*)&h;
}

// ---------------------------------------------------------------------------
// Persistent scan. Blocks 0..31: BC (batch). Blocks 32..223: GEMM.
// GEMM block g=cg*2+bg: cols [cg*48,+48), batches [bg*16,+16).
//   cg<32:  fp32 Wcat, K=576 (th/vA/vB path — argmax-sensitive, full precision)
//   cg>=32: bf16 Wb16, K=512 (gate path; rows 512:576 structurally zero)
// Thread tile 4b x 3c per K-seg. LINE-SPACED flags (r11's dense packing
// hot-banked the LLC: 16 writers + 224 pollers per line — measured +1.8us/step).
// ---------------------------------------------------------------------------
__global__ __launch_bounds__(NTHR, 1) void persist_kernel(
    const float* __restrict__ P1, const float* __restrict__ P2,
    const float* __restrict__ Wcat, const unsigned short* __restrict__ Wb16,
    float* __restrict__ oc, float* __restrict__ hTx_all,
    float* __restrict__ hnew_part, float* __restrict__ whh_part,
    const float* __restrict__ c0, const float* __restrict__ fc1_w,
    const float* __restrict__ fc1_b, const float* __restrict__ fc2_b,
    const float* __restrict__ u_noise, const int* __restrict__ length,
    const float* __restrict__ fc_w, const float* __restrict__ fc_b,
    float* __restrict__ out, int* __restrict__ bar)
{
  __shared__ float smem[15424];    // GEMM: hxs[9216] + red[8*776]; BC: scratch
  const int bid = blockIdx.x;
  const int tid = threadIdx.x;

  if (bid >= 32) {
    // ================= GEMM block =================
    const int gb  = bid - 32;            // 0..191
    const int cg  = gb >> 1;             // 0..95
    const int bg  = gb & 1;              // batch half
    const bool late = (cg >= 32);
    const int colbase = cg * 48;
    const int s   = tid >> 6;            // K-seg 0..7
    const int c   = (tid >> 2) & 15;     // col-triple 0..15
    const int bq  = tid & 3;             // batch-quad 0..3
    const int seg = late ? 64 : 72;
    const int kbase = s * seg;
    const int stageN = late ? 2048 : 2304;   // float4 count (8192 / 9216 floats)
    float* hxs = smem;                   // [576][16] k-major (this batch-half)
    float* red = smem + 9216;            // [8][776]

    for (int t = 0; t < 128; ++t) {
      // wait for my 16 batches' h(t): line-spaced flags, 16 parallel pollers
      if (tid < 16) {
        while (cohLoadI(&bar[(bg*16 + tid)*32]) < t) __builtin_amdgcn_s_sleep(1);
      }
      __syncthreads();
      // stage hx half (k-major; late blocks skip rows 512:576)
      const float* hsrc = hTx_all + (size_t)t*HTXS + bg*9216;
      for (int i = tid; i < stageN; i += NTHR)
        *(float4*)(hxs + i*4) = *(const float4*)(hsrc + i*4);
      __syncthreads();
      // 4 batches x 3 cols register tile
      float acc[4][3];
      #pragma unroll
      for (int bi = 0; bi < 4; ++bi)
        #pragma unroll
        for (int cj = 0; cj < 3; ++cj) acc[bi][cj] = 0.f;
      const float* hp = hxs + kbase*16 + bq*4;
      if (!late) {
        const float* wp = Wcat + (size_t)kbase*4608 + colbase + c*3;
        #pragma unroll 4
        for (int kk = 0; kk < 72; ++kk) {
          float4 h4 = *(const float4*)(hp); hp += 16;
          float w0 = wp[0], w1 = wp[1], w2 = wp[2]; wp += 4608;
          acc[0][0] += h4.x*w0; acc[0][1] += h4.x*w1; acc[0][2] += h4.x*w2;
          acc[1][0] += h4.y*w0; acc[1][1] += h4.y*w1; acc[1][2] += h4.y*w2;
          acc[2][0] += h4.z*w0; acc[2][1] += h4.z*w1; acc[2][2] += h4.z*w2;
          acc[3][0] += h4.w*w0; acc[3][1] += h4.w*w1; acc[3][2] += h4.w*w2;
        }
      } else {
        const unsigned short* wp = Wb16 + (size_t)kbase*3072 + (colbase - 1536) + c*3;
        #pragma unroll 4
        for (int kk = 0; kk < 64; ++kk) {
          float4 h4 = *(const float4*)(hp); hp += 16;
          float w0 = bf2f(wp[0]), w1 = bf2f(wp[1]), w2 = bf2f(wp[2]); wp += 3072;
          acc[0][0] += h4.x*w0; acc[0][1] += h4.x*w1; acc[0][2] += h4.x*w2;
          acc[1][0] += h4.y*w0; acc[1][1] += h4.y*w1; acc[1][2] += h4.y*w2;
          acc[2][0] += h4.z*w0; acc[2][1] += h4.z*w1; acc[2][2] += h4.z*w2;
          acc[3][0] += h4.w*w0; acc[3][1] += h4.w*w1; acc[3][2] += h4.w*w2;
        }
      }
      {
        float* rp = red + s*776 + (bq*4)*48 + c*3;
        #pragma unroll
        for (int bi = 0; bi < 4; ++bi) {
          rp[bi*48 + 0] = acc[bi][0];
          rp[bi*48 + 1] = acc[bi][1];
          rp[bi*48 + 2] = acc[bi][2];
        }
      }
      __syncthreads();
      // 8-seg reduce + sc1 store to oc
      for (int i = tid; i < 768; i += NTHR) {
        float ssum = 0.f;
        #pragma unroll
        for (int w = 0; w < 8; ++w) ssum += red[w*776 + i];
        int b16 = i / 48, cc = i - b16*48;
        cohStore(&oc[(size_t)(bg*16 + b16)*4608 + colbase + cc], ssum);
      }
      __syncthreads();                   // drain sc1 stores (vmcnt 0)
      if (tid == 0) cohStoreI(&bar[1024 + gb*32], t + 1);
    }
  } else {
    // ================= BC block: batch b =================
    const int b = bid;
    const int lenb = length[b];
    float hcur = 0.f;
    float usage_r = -99999.f;            // valid for tid<64
    int jprev = 0;                       // thread-0 only
    int* flg = (int*)(smem + 1100);
    const float c0r = c0[tid], c0z = c0[512 + tid], c0n = c0[1024 + tid];
    const float fc2bv = fc2_b[tid];
    const float f1b = (tid < 64) ? fc1_b[tid] : 0.f;
    const int n_ = tid & 63, kg_ = tid >> 6;
    const float* fw = fc1_w + (size_t)kg_*64*64 + n_;

    for (int t = 0; t < 128; ++t) {
      const int t32b = t*32 + b;
      // prefetch step inputs (independent of flags)
      const float* p1p = P1 + (size_t)t32b*1536;
      float p1r = p1p[tid], p1z = p1p[512 + tid], p1n = p1p[1024 + tid];
      float p2v = P2[(size_t)t32b*512 + tid];
      float uval = (tid < 64) ? u_noise[(size_t)t32b*64 + tid] : 0.f;
      // ---- wait EARLY blocks (g 0..63): 64 line-spaced flags, 64 pollers ----
      if (tid < 64) {
        while (cohLoadI(&bar[1024 + tid*32]) < t + 1) __builtin_amdgcn_s_sleep(1);
      }
      __syncthreads();
      const float* ocb = oc + (size_t)b*4608;
      float oct = cohLoad(ocb + tid);
      float vA  = cohLoad(ocb + 512  + tid);
      float vB  = cohLoad(ocb + 1024 + tid);
      smem[tid] = tanhf(p2v + oct);      // th
      __syncthreads();
      {                                  // fc1 partial dots
        float sdot = 0.f;
        #pragma unroll 8
        for (int k = 0; k < 64; ++k) sdot += smem[kg_*64 + k] * fw[(size_t)k*64];
        smem[512 + tid] = sdot;
      }
      __syncthreads();
      if (tid < 64) {                    // logits + Gumbel + wave argmax
        float l = f1b;
        #pragma unroll
        for (int kg = 0; kg < 8; ++kg) l += smem[512 + kg*64 + tid];
        l += -logf(1e-20f - logf(1e-20f + uval));
        float best = l; int idx = tid;
        #pragma unroll
        for (int off = 32; off >= 1; off >>= 1) {
          float ob = __shfl_xor(best, off);
          int   oi = __shfl_xor(idx,  off);
          if (ob > best || (ob == best && oi < idx)) { best = ob; idx = oi; }
        }
        if (tid == 0) {
          flg[0] = idx;
          flg[1] = (t < 64) ? t : jprev;
          jprev = idx;
        }
      }
      // ---- wait LATE blocks (g 64..191): 128 line-spaced flags ----
      if (tid < 128) {
        while (cohLoadI(&bar[1024 + (64 + tid)*32]) < t + 1) __builtin_amdgcn_s_sleep(1);
      }
      __syncthreads();
      const int jj = flg[0], ss = flg[1];
      float vAW0 = cohLoad(ocb + 1536 + tid);
      float vAW1 = cohLoad(ocb + 2048 + tid);
      float vAW2 = cohLoad(ocb + 2560 + tid);
      float vBW0 = cohLoad(ocb + 3072 + tid);
      float vBW1 = cohLoad(ocb + 3584 + tid);
      float vBW2 = cohLoad(ocb + 4096 + tid);
      float hnp, w0, w1, w2;
      if (jj == ss) { hnp = vA; w0 = vAW0; w1 = vAW1; w2 = vAW2; }
      else {
        hnp = hnew_part[(size_t)(b*64 + jj)*512 + tid];
        const float* wpp = whh_part + (size_t)(b*64 + jj)*1536;
        w0 = wpp[tid]; w1 = wpp[512 + tid]; w2 = wpp[1024 + tid];
      }
      float h_new = hnp + vB + fc2bv;
      float wh_r = w0 + vBW0 + c0r;
      float wh_z = w1 + vBW1 + c0z;
      float wh_n = w2 + vBW2 + c0n;
      float r  = 1.f / (1.f + expf(-(p1r + wh_r)));
      float z  = 1.f / (1.f + expf(-(p1z + wh_z)));
      float nn = tanhf(p1n + r*wh_n);
      float h1 = (1.f - z)*nn + z*h_new;
      if (t >= lenb) h1 = hcur;
      hcur = h1;
      // publish h(t+1)+lu via sc1 (k-major [576][16], half b>>4)
      float* hw = hTx_all + (size_t)(t + 1)*HTXS + (b >> 4)*9216;
      cohStore(&hw[tid*16 + (b & 15)], h1);
      if (tid < 64) {
        float un = (usage_r - 1.f) * (tid == jj ? 0.f : 1.f);
        usage_r = un;
        cohStore(&hw[(512 + tid)*16 + (b & 15)], 1.f / (1.f + expf(-un)));
      }
      smem[tid] = h1;                    // for out projection below
      __syncthreads();                   // drain sc1 stores
      if (tid == 0) cohStoreI(&bar[b*32], t + 1);
      // ---- off critical path: slot caches + output projection ----
      hnew_part[(size_t)(b*64 + ss)*512 + tid] = vA;
      float* wps = whh_part + (size_t)(b*64 + ss)*1536;
      wps[tid] = vAW0; wps[512 + tid] = vAW1; wps[1024 + tid] = vAW2;
      {
        int a = tid & 31, jg = tid >> 5;
        float sp = 0.f;
        #pragma unroll 8
        for (int jx = 0; jx < 32; ++jx)
          sp += smem[jg*32 + jx] * fc_w[(size_t)(jg*32 + jx)*32 + a];
        smem[512 + tid] = sp;
      }
      __syncthreads();
      if (tid < 32) {
        float s2 = fc_b[tid];
        #pragma unroll
        for (int jg = 0; jg < 16; ++jg) s2 += smem[512 + jg*32 + tid];
        out[(size_t)t32b*32 + tid] = s2;
      }
    }
  }
}

// ---------------------------------------------------------------------------
extern "C" void kernel_launch(void* const* d_in, const int* in_sizes, int n_in,
                              void* d_out, int out_size, void* d_ws, size_t ws_size,
                              hipStream_t stream)
{
  const float* x      = (const float*)d_in[0];
  const int*   length = (const int*)  d_in[1];
  const float* u_nois = (const float*)d_in[2];
  const float* W_ih   = (const float*)d_in[3];
  const float* W_hh   = (const float*)d_in[4];
  const float* bias   = (const float*)d_in[5];
  const float* W_im   = (const float*)d_in[6];
  const float* W_hm   = (const float*)d_in[7];
  const float* W_um   = (const float*)d_in[8];
  const float* fc1_w  = (const float*)d_in[9];
  const float* fc1_b  = (const float*)d_in[10];
  const float* fc2_w  = (const float*)d_in[11];
  const float* fc2_b  = (const float*)d_in[12];
  const float* fc_w   = (const float*)d_in[13];
  const float* fc_b   = (const float*)d_in[14];
  float* out = (float*)d_out;

  float* ws   = (float*)d_ws;
  int*   bar  = (int*)d_ws;
  float* hTx  = ws + OFF_HTX;
  float* oc   = ws + OFF_OC;
  float* hnew = ws + OFF_HNEW;
  float* whh  = ws + OFF_WHH;
  float* c0   = ws + OFF_C0;
  float* Wcat = ws + OFF_WCAT;
  unsigned short* Wb16 = (unsigned short*)(ws + OFF_WB16);
  float* P1   = ws + OFF_P1;
  float* P2   = ws + OFF_P2;

  // zero: flag words + hTx buffer 0 (h=0, lu=0); slot caches (mem=0)
  hipMemsetAsync(d_ws, 0, (size_t)(OFF_HTX + HTXS) * sizeof(float), stream);
  hipMemsetAsync(hnew, 0, (size_t)(32*64*512 + 32*64*1536) * sizeof(float), stream);

  setup_kernel<<<2115, 512, 0, stream>>>(W_hm, fc2_w, W_um, W_hh, bias, fc2_b,
                                         Wcat, c0);

  // M_A = fc2_A@W_hh -> Wcat cols 1536:3072 ; M_B = fc2_B@W_hh -> 3072:4608
  { dim3 g(4, 24);
    gemm_f32<<<g, 256, 0, stream>>>(fc2_w,                   W_hh, nullptr, Wcat + 1536,
                                    512, 1536, 512, 512, 1536, 4608);
    gemm_f32<<<g, 256, 0, stream>>>(fc2_w + (size_t)512*512, W_hh, nullptr, Wcat + 3072,
                                    512, 1536, 512, 512, 1536, 4608); }
  // bf16 compaction of the gate-path composite weights
  cvt_kernel<<<3072, 512, 0, stream>>>(Wcat, Wb16);
  // P1 = x@W_ih + bias_ih ; P2 = x@W_im
  { dim3 g(32, 24);
    gemm_f32<<<g, 256, 0, stream>>>(x, W_ih, bias, P1, 4096, 1536, 512, 512, 1536, 1536); }
  { dim3 g(32, 8);
    gemm_f32<<<g, 256, 0, stream>>>(x, W_im, nullptr, P2, 4096, 512, 512, 512, 512, 512); }

  persist_kernel<<<NBLK, NTHR, 0, stream>>>(P1, P2, Wcat, Wb16, oc, hTx, hnew,
                                            whh, c0, fc1_w, fc1_b, fc2_b,
                                            u_nois, length, fc_w, fc_b, out, bar);
}